// Round 2
// baseline (2630.251 us; speedup 1.0000x reference)
//
#include <hip/hip_runtime.h>

#define NC 96
#define NC3 288
#define NH 256
#define NW 256
#define NHW 65536

// ---------------- 1x1 conv (QKV proj and output proj) ----------------
// out[b][o][s] = sum_c in[b][c][s] * w[o][c] + bias[o]   (b within chunk)
template <int OUTC>
__global__ __launch_bounds__(512) void k_conv1x1(
    const float* __restrict__ in, const float* __restrict__ w,
    const float* __restrict__ bias, float* __restrict__ out) {
  __shared__ float xs[NC][256];
  const int t = threadIdx.x;
  const int s = t & 255, half = t >> 8;
  const int blk = blockIdx.x;
  const int b = blk >> 8, s0 = (blk & 255) << 8;
  const float* xb = in + (size_t)b * NC * NHW + s0;
  for (int idx = t; idx < NC * 256; idx += 512)
    xs[idx >> 8][idx & 255] = xb[(size_t)(idx >> 8) * NHW + (idx & 255)];
  __syncthreads();
  float* ob = out + (size_t)b * OUTC * NHW + s0;
  for (int oc = half * 16; oc < OUTC; oc += 32) {
    float acc[16];
#pragma unroll
    for (int o = 0; o < 16; ++o) acc[o] = 0.f;
    for (int c = 0; c < NC; ++c) {
      const float xv = xs[c][s];
#pragma unroll
      for (int o = 0; o < 16; ++o)
        acc[o] = fmaf(xv, w[(oc + o) * NC + c], acc[o]);
    }
#pragma unroll
    for (int o = 0; o < 16; ++o)
      ob[(size_t)(oc + o) * NHW + s] = acc[o] + bias[oc + o];
  }
}

// ---------------- depthwise 3x3, pad=1 ----------------
__global__ __launch_bounds__(256) void k_dw(
    const float* __restrict__ in, const float* __restrict__ w,
    const float* __restrict__ bias, float* __restrict__ out) {
  __shared__ float s[10][NW + 2];
  const int t = threadIdx.x;
  const int bc = blockIdx.y;          // b*NC3 + ch  (b within chunk)
  const int ch = bc % NC3;
  const int h0 = blockIdx.x * 8;
  const float* ib = in + (size_t)bc * NHW;
  for (int idx = t; idx < 10 * (NW + 2); idx += 256) {
    const int r = idx / (NW + 2), cc = idx % (NW + 2);
    const int gh = h0 + r - 1, gw = cc - 1;
    float v = 0.f;
    if (gh >= 0 && gh < NH && gw >= 0 && gw < NW) v = ib[gh * NW + gw];
    s[r][cc] = v;
  }
  __syncthreads();
  float wr[9];
#pragma unroll
  for (int k = 0; k < 9; ++k) wr[k] = w[ch * 9 + k];
  const float bs = bias[ch];
  float* ob = out + (size_t)bc * NHW + (size_t)h0 * NW + t;
#pragma unroll
  for (int r = 0; r < 8; ++r) {
    float a = bs;
#pragma unroll
    for (int dr = 0; dr < 3; ++dr)
#pragma unroll
      for (int dc = 0; dc < 3; ++dc)
        a = fmaf(s[r + dr][t + dc], wr[dr * 3 + dc], a);
    ob[r * NW] = a;
  }
}

// ---------------- per-(b,c,w) inverse L2 norms over H for q,k ----------------
__global__ __launch_bounds__(256) void k_norm(
    const float* __restrict__ qkv, float* __restrict__ invq,
    float* __restrict__ invk) {
  const int bc = blockIdx.x;  // b*NC + c
  const int b = bc / NC, c = bc % NC;
  const int t = threadIdx.x;
  const float* q = qkv + ((size_t)b * NC3 + c) * NHW;
  const float* k = qkv + ((size_t)b * NC3 + NC + c) * NHW;
  float sq = 0.f, sk = 0.f;
  for (int h = 0; h < NH; ++h) {
    const float a = q[h * NW + t];
    sq = fmaf(a, a, sq);
    const float d = k[h * NW + t];
    sk = fmaf(d, d, sk);
  }
  invq[bc * NW + t] = 1.f / fmaxf(sqrtf(sq), 1e-12f);
  invk[bc * NW + t] = 1.f / fmaxf(sqrtf(sk), 1e-12f);
}

// ---------------- attn = colsoftmax( (Qn^T Kn) * temp[c] ) ----------------
__global__ __launch_bounds__(256) void k_attn(
    const float* __restrict__ qkv, const float* __restrict__ invq,
    const float* __restrict__ invk, const float* __restrict__ temp,
    float* __restrict__ attn) {
  __shared__ float Qs[32][256];
  __shared__ float Ks[32][64];
  const int t = threadIdx.x;
  const int v0 = blockIdx.x * 32;  // v set: v0+[0,32) u v0+128+[0,32)
  const int bc = blockIdx.y;
  const int b = bc / NC, c = bc % NC;
  const float* qg = qkv + ((size_t)b * NC3 + c) * NHW;
  const float* kg = qkv + ((size_t)b * NC3 + NC + c) * NHW;
  const int wg = t & 31, vg = t >> 5;
  float acc[8][8];
#pragma unroll
  for (int i = 0; i < 8; ++i)
#pragma unroll
    for (int j = 0; j < 8; ++j) acc[i][j] = 0.f;

  for (int h0 = 0; h0 < NH; h0 += 32) {
#pragma unroll
    for (int m = 0; m < 8; ++m) {
      const int fi = t + 256 * m;
      const int hh = fi >> 6, w4 = (fi & 63) << 2;
      *(float4*)&Qs[hh][w4] = *(const float4*)&qg[(size_t)(h0 + hh) * NW + w4];
    }
#pragma unroll
    for (int m = 0; m < 2; ++m) {
      const int fi = t + 256 * m;
      const int hh = fi >> 4, s4 = fi & 15;
      const int col = v0 + (s4 < 8 ? 4 * s4 : 96 + 4 * s4);
      *(float4*)&Ks[hh][4 * s4] = *(const float4*)&kg[(size_t)(h0 + hh) * NW + col];
    }
    __syncthreads();
#pragma unroll 4
    for (int hh = 0; hh < 32; ++hh) {
      const float4 q0 = *(const float4*)&Qs[hh][4 * wg];
      const float4 q1 = *(const float4*)&Qs[hh][128 + 4 * wg];
      const float4 k0 = *(const float4*)&Ks[hh][4 * vg];
      const float4 k1 = *(const float4*)&Ks[hh][32 + 4 * vg];
      const float qv[8] = {q0.x, q0.y, q0.z, q0.w, q1.x, q1.y, q1.z, q1.w};
      const float kv[8] = {k0.x, k0.y, k0.z, k0.w, k1.x, k1.y, k1.z, k1.w};
#pragma unroll
      for (int i = 0; i < 8; ++i)
#pragma unroll
        for (int j = 0; j < 8; ++j)
          acc[i][j] = fmaf(qv[i], kv[j], acc[i][j]);
    }
    __syncthreads();
  }

  const float tc = temp[c];
  float iq[8], ik[8];
#pragma unroll
  for (int i = 0; i < 8; ++i)
    iq[i] = invq[bc * NW + 4 * wg + (i & 3) + 128 * (i >> 2)];
#pragma unroll
  for (int j = 0; j < 8; ++j)
    ik[j] = invk[bc * NW + v0 + 4 * vg + (j & 3) + ((j >> 2) ? 128 : 0)] * tc;
#pragma unroll
  for (int i = 0; i < 8; ++i)
#pragma unroll
    for (int j = 0; j < 8; ++j) acc[i][j] *= iq[i] * ik[j];

  float mx[8], sm[8];
#pragma unroll
  for (int j = 0; j < 8; ++j) {
    float m = acc[0][j];
#pragma unroll
    for (int i = 1; i < 8; ++i) m = fmaxf(m, acc[i][j]);
#pragma unroll
    for (int d = 1; d < 32; d <<= 1) m = fmaxf(m, __shfl_xor(m, d));
    mx[j] = m;
  }
#pragma unroll
  for (int j = 0; j < 8; ++j) {
    float ss = 0.f;
#pragma unroll
    for (int i = 0; i < 8; ++i) {
      const float p = __expf(acc[i][j] - mx[j]);
      acc[i][j] = p;
      ss += p;
    }
#pragma unroll
    for (int d = 1; d < 32; d <<= 1) ss += __shfl_xor(ss, d);
    sm[j] = 1.f / ss;
  }
#pragma unroll
  for (int i = 0; i < 8; ++i)
#pragma unroll
    for (int j = 0; j < 8; ++j) acc[i][j] *= sm[j];

  float* ab = attn + (size_t)bc * NHW;
#pragma unroll
  for (int i = 0; i < 8; ++i) {
    const int wr = 4 * wg + (i & 3) + 128 * (i >> 2);
    const float4 o0 = make_float4(acc[i][0], acc[i][1], acc[i][2], acc[i][3]);
    const float4 o1 = make_float4(acc[i][4], acc[i][5], acc[i][6], acc[i][7]);
    *(float4*)&ab[(size_t)wr * NW + v0 + 4 * vg] = o0;
    *(float4*)&ab[(size_t)wr * NW + v0 + 128 + 4 * vg] = o1;
  }
}

// ---------------- out[h][v] = sum_w V[h][w] * attn[w][v] ----------------
__global__ __launch_bounds__(256) void k_av(
    const float* __restrict__ qkv, const float* __restrict__ attn,
    float* __restrict__ out) {
  __shared__ float Vt[32][132];  // [w][h], padded
  __shared__ float At[32][128];  // [w][v]
  const int t = threadIdx.x;
  const int tile = blockIdx.x;  // ht*2 + vt
  const int bc = blockIdx.y;
  const int b = bc / NC, c = bc % NC;
  const int h0 = (tile >> 1) * 128, v0 = (tile & 1) * 128;
  const float* vgp = qkv + ((size_t)b * NC3 + 2 * NC + c) * NHW;
  const float* ag = attn + (size_t)bc * NHW;
  const int hg = t & 15, vg = t >> 4;
  float acc[8][8];
#pragma unroll
  for (int i = 0; i < 8; ++i)
#pragma unroll
    for (int j = 0; j < 8; ++j) acc[i][j] = 0.f;

  for (int w0 = 0; w0 < NW; w0 += 32) {
#pragma unroll
    for (int m = 0; m < 4; ++m) {
      const int fi = t + 256 * m;
      const int hl = fi >> 3, w4 = (fi & 7) << 2;
      const float4 f = *(const float4*)&vgp[(size_t)(h0 + hl) * NW + w0 + w4];
      Vt[w4][hl] = f.x;
      Vt[w4 + 1][hl] = f.y;
      Vt[w4 + 2][hl] = f.z;
      Vt[w4 + 3][hl] = f.w;
    }
#pragma unroll
    for (int m = 0; m < 4; ++m) {
      const int fi = t + 256 * m;
      const int wl = fi >> 5, c4 = (fi & 31) << 2;
      *(float4*)&At[wl][c4] = *(const float4*)&ag[(size_t)(w0 + wl) * NW + v0 + c4];
    }
    __syncthreads();
#pragma unroll 4
    for (int kk = 0; kk < 32; ++kk) {
      const float4 a0 = *(const float4*)&Vt[kk][4 * hg];
      const float4 a1 = *(const float4*)&Vt[kk][64 + 4 * hg];
      const float4 b0 = *(const float4*)&At[kk][4 * vg];
      const float4 b1 = *(const float4*)&At[kk][64 + 4 * vg];
      const float hv[8] = {a0.x, a0.y, a0.z, a0.w, a1.x, a1.y, a1.z, a1.w};
      const float vv[8] = {b0.x, b0.y, b0.z, b0.w, b1.x, b1.y, b1.z, b1.w};
#pragma unroll
      for (int i = 0; i < 8; ++i)
#pragma unroll
        for (int j = 0; j < 8; ++j)
          acc[i][j] = fmaf(hv[i], vv[j], acc[i][j]);
    }
    __syncthreads();
  }

  float* ob = out + (size_t)bc * NHW;
#pragma unroll
  for (int i = 0; i < 8; ++i) {
    const int h = h0 + 4 * hg + (i & 3) + 64 * (i >> 2);
    const float4 o0 = make_float4(acc[i][0], acc[i][1], acc[i][2], acc[i][3]);
    const float4 o1 = make_float4(acc[i][4], acc[i][5], acc[i][6], acc[i][7]);
    *(float4*)&ob[(size_t)h * NW + v0 + 4 * vg] = o0;
    *(float4*)&ob[(size_t)h * NW + v0 + 64 + 4 * vg] = o1;
  }
}

extern "C" void kernel_launch(void* const* d_in, const int* in_sizes, int n_in,
                              void* d_out, int out_size, void* d_ws,
                              size_t ws_size, hipStream_t stream) {
  const float* x = (const float*)d_in[0];
  const float* qkv_w = (const float*)d_in[1];
  const float* qkv_b = (const float*)d_in[2];
  const float* dw_w = (const float*)d_in[3];
  const float* dw_b = (const float*)d_in[4];
  const float* temp = (const float*)d_in[5];
  const float* proj_w = (const float*)d_in[6];
  const float* proj_b = (const float*)d_in[7];
  float* out = (float*)d_out;

  // Adaptive batch chunking so workspace fits ws_size.
  // Per chunk of nb batches: qkv_raw + qkv_dw (nb*NC3*NHW each) + invq/invk.
  auto need = [](int nb) -> size_t {
    return (size_t)nb * NC3 * NHW * 4ull * 2ull + 2ull * nb * NC * NW * 4ull;
  };
  int nb = 1;
  if (need(4) <= ws_size) nb = 4;
  else if (need(2) <= ws_size) nb = 2;

  float* qkv_raw = (float*)d_ws;
  float* qkv_dw = qkv_raw + (size_t)nb * NC3 * NHW;
  float* invq = qkv_dw + (size_t)nb * NC3 * NHW;
  float* invk = invq + (size_t)nb * NC * NW;
  float* attn = qkv_raw;                               // alias (dead after dw)
  float* aout = qkv_raw + (size_t)nb * NC * NHW;       // alias, disjoint from attn

  for (int b0 = 0; b0 < 4; b0 += nb) {
    const float* xb = x + (size_t)b0 * NC * NHW;
    float* outb = out + (size_t)b0 * NC * NHW;
    k_conv1x1<NC3><<<dim3(nb * 256), 512, 0, stream>>>(xb, qkv_w, qkv_b, qkv_raw);
    k_dw<<<dim3(32, nb * NC3), 256, 0, stream>>>(qkv_raw, dw_w, dw_b, qkv_dw);
    k_norm<<<dim3(nb * NC), 256, 0, stream>>>(qkv_dw, invq, invk);
    k_attn<<<dim3(4, nb * NC), 256, 0, stream>>>(qkv_dw, invq, invk, temp, attn);
    k_av<<<dim3(4, nb * NC), 256, 0, stream>>>(qkv_dw, attn, aout);
    k_conv1x1<NC><<<dim3(nb * 256), 512, 0, stream>>>(aout, proj_w, proj_b, outb);
  }
}

// Round 3
// 849.733 us; speedup vs baseline: 3.0954x; 3.0954x over previous
//
#include <hip/hip_runtime.h>

#define NC 96
#define NC3 288
#define NH 256
#define NW 256
#define NHW 65536

// ---------------- 1x1 conv as GEMM: out[b][o][s] = sum_c x[b][c][s]*w[o][c]+bias[o]
// Block: 256 thr = 8 oc-groups x 32 spatial-threads. Tile: 96 oc x 128 spatial.
// W tile (96x96, 36KB) in LDS, broadcast float4 reads; X streamed from global.
template <int OUTC>
__global__ __launch_bounds__(256) void k_conv1x1(
    const float* __restrict__ in, const float* __restrict__ w,
    const float* __restrict__ bias, float* __restrict__ out) {
  __shared__ float ws_[96][96];
  const int t = threadIdx.x;
  const int b = blockIdx.z;
  const int oct = blockIdx.y;
  const int s0 = blockIdx.x * 128;

  const float* wt = w + (size_t)oct * 96 * NC;  // 96 rows of 96, contiguous
  for (int i = t; i < 96 * 96 / 4; i += 256)
    *(float4*)&ws_[0][i * 4] = *(const float4*)&wt[i * 4];
  __syncthreads();

  const int sg = t & 31;   // spatial thread (4 floats each)
  const int g = t >> 5;    // oc group: oc_local = g*12 + [0,12)
  const float* xb = in + (size_t)b * NC * NHW + s0 + 4 * sg;

  float4 acc[12];
#pragma unroll
  for (int o = 0; o < 12; ++o) acc[o] = make_float4(0.f, 0.f, 0.f, 0.f);

  for (int c0 = 0; c0 < NC; c0 += 4) {
    const float4 x0 = *(const float4*)&xb[(size_t)(c0 + 0) * NHW];
    const float4 x1 = *(const float4*)&xb[(size_t)(c0 + 1) * NHW];
    const float4 x2 = *(const float4*)&xb[(size_t)(c0 + 2) * NHW];
    const float4 x3 = *(const float4*)&xb[(size_t)(c0 + 3) * NHW];
#pragma unroll
    for (int o = 0; o < 12; ++o) {
      const float4 wv = *(const float4*)&ws_[g * 12 + o][c0];
      acc[o].x = fmaf(wv.x, x0.x, acc[o].x);
      acc[o].y = fmaf(wv.x, x0.y, acc[o].y);
      acc[o].z = fmaf(wv.x, x0.z, acc[o].z);
      acc[o].w = fmaf(wv.x, x0.w, acc[o].w);
      acc[o].x = fmaf(wv.y, x1.x, acc[o].x);
      acc[o].y = fmaf(wv.y, x1.y, acc[o].y);
      acc[o].z = fmaf(wv.y, x1.z, acc[o].z);
      acc[o].w = fmaf(wv.y, x1.w, acc[o].w);
      acc[o].x = fmaf(wv.z, x2.x, acc[o].x);
      acc[o].y = fmaf(wv.z, x2.y, acc[o].y);
      acc[o].z = fmaf(wv.z, x2.z, acc[o].z);
      acc[o].w = fmaf(wv.z, x2.w, acc[o].w);
      acc[o].x = fmaf(wv.w, x3.x, acc[o].x);
      acc[o].y = fmaf(wv.w, x3.y, acc[o].y);
      acc[o].z = fmaf(wv.w, x3.z, acc[o].z);
      acc[o].w = fmaf(wv.w, x3.w, acc[o].w);
    }
  }

  const int ocb = oct * 96 + g * 12;
  float* ob = out + (size_t)b * OUTC * NHW + (size_t)ocb * NHW + s0 + 4 * sg;
#pragma unroll
  for (int o = 0; o < 12; ++o) {
    const float bs = bias[ocb + o];
    float4 r = acc[o];
    r.x += bs; r.y += bs; r.z += bs; r.w += bs;
    *(float4*)&ob[(size_t)o * NHW] = r;
  }
}

// ---------------- depthwise 3x3, pad=1 ----------------
__global__ __launch_bounds__(256) void k_dw(
    const float* __restrict__ in, const float* __restrict__ w,
    const float* __restrict__ bias, float* __restrict__ out) {
  __shared__ float s[10][NW + 2];
  const int t = threadIdx.x;
  const int bc = blockIdx.y;          // b*NC3 + ch  (b within chunk)
  const int ch = bc % NC3;
  const int h0 = blockIdx.x * 8;
  const float* ib = in + (size_t)bc * NHW;
  for (int idx = t; idx < 10 * (NW + 2); idx += 256) {
    const int r = idx / (NW + 2), cc = idx % (NW + 2);
    const int gh = h0 + r - 1, gw = cc - 1;
    float v = 0.f;
    if (gh >= 0 && gh < NH && gw >= 0 && gw < NW) v = ib[gh * NW + gw];
    s[r][cc] = v;
  }
  __syncthreads();
  float wr[9];
#pragma unroll
  for (int k = 0; k < 9; ++k) wr[k] = w[ch * 9 + k];
  const float bs = bias[ch];
  float* ob = out + (size_t)bc * NHW + (size_t)h0 * NW + t;
#pragma unroll
  for (int r = 0; r < 8; ++r) {
    float a = bs;
#pragma unroll
    for (int dr = 0; dr < 3; ++dr)
#pragma unroll
      for (int dc = 0; dc < 3; ++dc)
        a = fmaf(s[r + dr][t + dc], wr[dr * 3 + dc], a);
    ob[r * NW] = a;
  }
}

// ---------------- per-(b,c,w) inverse L2 norms over H for q,k ----------------
__global__ __launch_bounds__(256) void k_norm(
    const float* __restrict__ qkv, float* __restrict__ invq,
    float* __restrict__ invk) {
  const int bc = blockIdx.x;  // b*NC + c
  const int b = bc / NC, c = bc % NC;
  const int t = threadIdx.x;
  const float* q = qkv + ((size_t)b * NC3 + c) * NHW;
  const float* k = qkv + ((size_t)b * NC3 + NC + c) * NHW;
  float sq = 0.f, sk = 0.f;
  for (int h = 0; h < NH; ++h) {
    const float a = q[h * NW + t];
    sq = fmaf(a, a, sq);
    const float d = k[h * NW + t];
    sk = fmaf(d, d, sk);
  }
  invq[bc * NW + t] = 1.f / fmaxf(sqrtf(sq), 1e-12f);
  invk[bc * NW + t] = 1.f / fmaxf(sqrtf(sk), 1e-12f);
}

// ---------------- attn = colsoftmax( (Qn^T Kn) * temp[c] ) ----------------
__global__ __launch_bounds__(256) void k_attn(
    const float* __restrict__ qkv, const float* __restrict__ invq,
    const float* __restrict__ invk, const float* __restrict__ temp,
    float* __restrict__ attn) {
  __shared__ float Qs[32][256];
  __shared__ float Ks[32][64];
  const int t = threadIdx.x;
  const int v0 = blockIdx.x * 32;  // v set: v0+[0,32) u v0+128+[0,32)
  const int bc = blockIdx.y;
  const int b = bc / NC, c = bc % NC;
  const float* qg = qkv + ((size_t)b * NC3 + c) * NHW;
  const float* kg = qkv + ((size_t)b * NC3 + NC + c) * NHW;
  const int wg = t & 31, vg = t >> 5;
  float acc[8][8];
#pragma unroll
  for (int i = 0; i < 8; ++i)
#pragma unroll
    for (int j = 0; j < 8; ++j) acc[i][j] = 0.f;

  for (int h0 = 0; h0 < NH; h0 += 32) {
#pragma unroll
    for (int m = 0; m < 8; ++m) {
      const int fi = t + 256 * m;
      const int hh = fi >> 6, w4 = (fi & 63) << 2;
      *(float4*)&Qs[hh][w4] = *(const float4*)&qg[(size_t)(h0 + hh) * NW + w4];
    }
#pragma unroll
    for (int m = 0; m < 2; ++m) {
      const int fi = t + 256 * m;
      const int hh = fi >> 4, s4 = fi & 15;
      const int col = v0 + (s4 < 8 ? 4 * s4 : 96 + 4 * s4);
      *(float4*)&Ks[hh][4 * s4] = *(const float4*)&kg[(size_t)(h0 + hh) * NW + col];
    }
    __syncthreads();
#pragma unroll 4
    for (int hh = 0; hh < 32; ++hh) {
      const float4 q0 = *(const float4*)&Qs[hh][4 * wg];
      const float4 q1 = *(const float4*)&Qs[hh][128 + 4 * wg];
      const float4 k0 = *(const float4*)&Ks[hh][4 * vg];
      const float4 k1 = *(const float4*)&Ks[hh][32 + 4 * vg];
      const float qv[8] = {q0.x, q0.y, q0.z, q0.w, q1.x, q1.y, q1.z, q1.w};
      const float kv[8] = {k0.x, k0.y, k0.z, k0.w, k1.x, k1.y, k1.z, k1.w};
#pragma unroll
      for (int i = 0; i < 8; ++i)
#pragma unroll
        for (int j = 0; j < 8; ++j)
          acc[i][j] = fmaf(qv[i], kv[j], acc[i][j]);
    }
    __syncthreads();
  }

  const float tc = temp[c];
  float iq[8], ik[8];
#pragma unroll
  for (int i = 0; i < 8; ++i)
    iq[i] = invq[bc * NW + 4 * wg + (i & 3) + 128 * (i >> 2)];
#pragma unroll
  for (int j = 0; j < 8; ++j)
    ik[j] = invk[bc * NW + v0 + 4 * vg + (j & 3) + ((j >> 2) ? 128 : 0)] * tc;
#pragma unroll
  for (int i = 0; i < 8; ++i)
#pragma unroll
    for (int j = 0; j < 8; ++j) acc[i][j] *= iq[i] * ik[j];

  float mx[8], sm[8];
#pragma unroll
  for (int j = 0; j < 8; ++j) {
    float m = acc[0][j];
#pragma unroll
    for (int i = 1; i < 8; ++i) m = fmaxf(m, acc[i][j]);
#pragma unroll
    for (int d = 1; d < 32; d <<= 1) m = fmaxf(m, __shfl_xor(m, d));
    mx[j] = m;
  }
#pragma unroll
  for (int j = 0; j < 8; ++j) {
    float ss = 0.f;
#pragma unroll
    for (int i = 0; i < 8; ++i) {
      const float p = __expf(acc[i][j] - mx[j]);
      acc[i][j] = p;
      ss += p;
    }
#pragma unroll
    for (int d = 1; d < 32; d <<= 1) ss += __shfl_xor(ss, d);
    sm[j] = 1.f / ss;
  }
#pragma unroll
  for (int i = 0; i < 8; ++i)
#pragma unroll
    for (int j = 0; j < 8; ++j) acc[i][j] *= sm[j];

  float* ab = attn + (size_t)bc * NHW;
#pragma unroll
  for (int i = 0; i < 8; ++i) {
    const int wr = 4 * wg + (i & 3) + 128 * (i >> 2);
    const float4 o0 = make_float4(acc[i][0], acc[i][1], acc[i][2], acc[i][3]);
    const float4 o1 = make_float4(acc[i][4], acc[i][5], acc[i][6], acc[i][7]);
    *(float4*)&ab[(size_t)wr * NW + v0 + 4 * vg] = o0;
    *(float4*)&ab[(size_t)wr * NW + v0 + 128 + 4 * vg] = o1;
  }
}

// ---------------- out[h][v] = sum_w V[h][w] * attn[w][v] ----------------
__global__ __launch_bounds__(256) void k_av(
    const float* __restrict__ qkv, const float* __restrict__ attn,
    float* __restrict__ out) {
  __shared__ float Vt[32][132];  // [w][h], padded
  __shared__ float At[32][128];  // [w][v]
  const int t = threadIdx.x;
  const int tile = blockIdx.x;  // ht*2 + vt
  const int bc = blockIdx.y;
  const int b = bc / NC, c = bc % NC;
  const int h0 = (tile >> 1) * 128, v0 = (tile & 1) * 128;
  const float* vgp = qkv + ((size_t)b * NC3 + 2 * NC + c) * NHW;
  const float* ag = attn + (size_t)bc * NHW;
  const int hg = t & 15, vg = t >> 4;
  float acc[8][8];
#pragma unroll
  for (int i = 0; i < 8; ++i)
#pragma unroll
    for (int j = 0; j < 8; ++j) acc[i][j] = 0.f;

  for (int w0 = 0; w0 < NW; w0 += 32) {
#pragma unroll
    for (int m = 0; m < 4; ++m) {
      const int fi = t + 256 * m;
      const int hl = fi >> 3, w4 = (fi & 7) << 2;
      const float4 f = *(const float4*)&vgp[(size_t)(h0 + hl) * NW + w0 + w4];
      Vt[w4][hl] = f.x;
      Vt[w4 + 1][hl] = f.y;
      Vt[w4 + 2][hl] = f.z;
      Vt[w4 + 3][hl] = f.w;
    }
#pragma unroll
    for (int m = 0; m < 4; ++m) {
      const int fi = t + 256 * m;
      const int wl = fi >> 5, c4 = (fi & 31) << 2;
      *(float4*)&At[wl][c4] = *(const float4*)&ag[(size_t)(w0 + wl) * NW + v0 + c4];
    }
    __syncthreads();
#pragma unroll 4
    for (int kk = 0; kk < 32; ++kk) {
      const float4 a0 = *(const float4*)&Vt[kk][4 * hg];
      const float4 a1 = *(const float4*)&Vt[kk][64 + 4 * hg];
      const float4 b0 = *(const float4*)&At[kk][4 * vg];
      const float4 b1 = *(const float4*)&At[kk][64 + 4 * vg];
      const float hv[8] = {a0.x, a0.y, a0.z, a0.w, a1.x, a1.y, a1.z, a1.w};
      const float vv[8] = {b0.x, b0.y, b0.z, b0.w, b1.x, b1.y, b1.z, b1.w};
#pragma unroll
      for (int i = 0; i < 8; ++i)
#pragma unroll
        for (int j = 0; j < 8; ++j)
          acc[i][j] = fmaf(hv[i], vv[j], acc[i][j]);
    }
    __syncthreads();
  }

  float* ob = out + (size_t)bc * NHW;
#pragma unroll
  for (int i = 0; i < 8; ++i) {
    const int h = h0 + 4 * hg + (i & 3) + 64 * (i >> 2);
    const float4 o0 = make_float4(acc[i][0], acc[i][1], acc[i][2], acc[i][3]);
    const float4 o1 = make_float4(acc[i][4], acc[i][5], acc[i][6], acc[i][7]);
    *(float4*)&ob[(size_t)h * NW + v0 + 4 * vg] = o0;
    *(float4*)&ob[(size_t)h * NW + v0 + 64 + 4 * vg] = o1;
  }
}

extern "C" void kernel_launch(void* const* d_in, const int* in_sizes, int n_in,
                              void* d_out, int out_size, void* d_ws,
                              size_t ws_size, hipStream_t stream) {
  const float* x = (const float*)d_in[0];
  const float* qkv_w = (const float*)d_in[1];
  const float* qkv_b = (const float*)d_in[2];
  const float* dw_w = (const float*)d_in[3];
  const float* dw_b = (const float*)d_in[4];
  const float* temp = (const float*)d_in[5];
  const float* proj_w = (const float*)d_in[6];
  const float* proj_b = (const float*)d_in[7];
  float* out = (float*)d_out;

  // Adaptive batch chunking so workspace fits ws_size.
  auto need = [](int nb) -> size_t {
    return (size_t)nb * NC3 * NHW * 4ull * 2ull + 2ull * nb * NC * NW * 4ull;
  };
  int nb = 1;
  if (need(4) <= ws_size) nb = 4;
  else if (need(2) <= ws_size) nb = 2;

  float* qkv_raw = (float*)d_ws;
  float* qkv_dw = qkv_raw + (size_t)nb * NC3 * NHW;
  float* invq = qkv_dw + (size_t)nb * NC3 * NHW;
  float* invk = invq + (size_t)nb * NC * NW;
  float* attn = qkv_raw;                               // alias (dead after dw)
  float* aout = qkv_raw + (size_t)nb * NC * NHW;       // alias, disjoint from attn

  for (int b0 = 0; b0 < 4; b0 += nb) {
    const float* xb = x + (size_t)b0 * NC * NHW;
    float* outb = out + (size_t)b0 * NC * NHW;
    k_conv1x1<NC3><<<dim3(512, 3, nb), 256, 0, stream>>>(xb, qkv_w, qkv_b, qkv_raw);
    k_dw<<<dim3(32, nb * NC3), 256, 0, stream>>>(qkv_raw, dw_w, dw_b, qkv_dw);
    k_norm<<<dim3(nb * NC), 256, 0, stream>>>(qkv_dw, invq, invk);
    k_attn<<<dim3(4, nb * NC), 256, 0, stream>>>(qkv_dw, invq, invk, temp, attn);
    k_av<<<dim3(4, nb * NC), 256, 0, stream>>>(qkv_dw, attn, aout);
    k_conv1x1<NC><<<dim3(512, 1, nb), 256, 0, stream>>>(aout, proj_w, proj_b, outb);
  }
}

// Round 4
// 684.294 us; speedup vs baseline: 3.8437x; 1.2418x over previous
//
#include <hip/hip_runtime.h>

#define NC 96
#define NC3 288
#define NH 256
#define NW 256
#define NHW 65536

typedef unsigned short ushort_t;
typedef __attribute__((ext_vector_type(8))) short bf16x8;
typedef __attribute__((ext_vector_type(4))) float f32x4;

__device__ __forceinline__ ushort_t f2bf(float x) {
  unsigned u = __float_as_uint(x);
  u += 0x7fffu + ((u >> 16) & 1u);
  return (ushort_t)(u >> 16);
}
__device__ __forceinline__ float bf2f(ushort_t h) {
  return __uint_as_float((unsigned)h << 16);
}

// ---------------- 1x1 conv as GEMM (unchanged from R3) ----------------
template <int OUTC>
__global__ __launch_bounds__(256) void k_conv1x1(
    const float* __restrict__ in, const float* __restrict__ w,
    const float* __restrict__ bias, float* __restrict__ out) {
  __shared__ float ws_[96][96];
  const int t = threadIdx.x;
  const int b = blockIdx.z;
  const int oct = blockIdx.y;
  const int s0 = blockIdx.x * 128;

  const float* wt = w + (size_t)oct * 96 * NC;
  for (int i = t; i < 96 * 96 / 4; i += 256)
    *(float4*)&ws_[0][i * 4] = *(const float4*)&wt[i * 4];
  __syncthreads();

  const int sg = t & 31;
  const int g = t >> 5;
  const float* xb = in + (size_t)b * NC * NHW + s0 + 4 * sg;

  float4 acc[12];
#pragma unroll
  for (int o = 0; o < 12; ++o) acc[o] = make_float4(0.f, 0.f, 0.f, 0.f);

  for (int c0 = 0; c0 < NC; c0 += 4) {
    const float4 x0 = *(const float4*)&xb[(size_t)(c0 + 0) * NHW];
    const float4 x1 = *(const float4*)&xb[(size_t)(c0 + 1) * NHW];
    const float4 x2 = *(const float4*)&xb[(size_t)(c0 + 2) * NHW];
    const float4 x3 = *(const float4*)&xb[(size_t)(c0 + 3) * NHW];
#pragma unroll
    for (int o = 0; o < 12; ++o) {
      const float4 wv = *(const float4*)&ws_[g * 12 + o][c0];
      acc[o].x = fmaf(wv.x, x0.x, acc[o].x);
      acc[o].y = fmaf(wv.x, x0.y, acc[o].y);
      acc[o].z = fmaf(wv.x, x0.z, acc[o].z);
      acc[o].w = fmaf(wv.x, x0.w, acc[o].w);
      acc[o].x = fmaf(wv.y, x1.x, acc[o].x);
      acc[o].y = fmaf(wv.y, x1.y, acc[o].y);
      acc[o].z = fmaf(wv.y, x1.z, acc[o].z);
      acc[o].w = fmaf(wv.y, x1.w, acc[o].w);
      acc[o].x = fmaf(wv.z, x2.x, acc[o].x);
      acc[o].y = fmaf(wv.z, x2.y, acc[o].y);
      acc[o].z = fmaf(wv.z, x2.z, acc[o].z);
      acc[o].w = fmaf(wv.z, x2.w, acc[o].w);
      acc[o].x = fmaf(wv.w, x3.x, acc[o].x);
      acc[o].y = fmaf(wv.w, x3.y, acc[o].y);
      acc[o].z = fmaf(wv.w, x3.z, acc[o].z);
      acc[o].w = fmaf(wv.w, x3.w, acc[o].w);
    }
  }

  const int ocb = oct * 96 + g * 12;
  float* ob = out + (size_t)b * OUTC * NHW + (size_t)ocb * NHW + s0 + 4 * sg;
#pragma unroll
  for (int o = 0; o < 12; ++o) {
    const float bs = bias[ocb + o];
    float4 r = acc[o];
    r.x += bs; r.y += bs; r.z += bs; r.w += bs;
    *(float4*)&ob[(size_t)o * NHW] = r;
  }
}

// ---------------- depthwise 3x3, pad=1; V channels -> split bf16 tiled ----
// Q,K (ch<192): fp32 to out_qk [b*192+ch][h][w]
// V (ch>=192): bf16 hi/lo to v_* tiled [bcv][wb][h][32w]
__global__ __launch_bounds__(256) void k_dw2(
    const float* __restrict__ in, const float* __restrict__ w,
    const float* __restrict__ bias, float* __restrict__ out_qk,
    ushort_t* __restrict__ v_hi, ushort_t* __restrict__ v_lo) {
  __shared__ float s[10][NW + 2];
  const int t = threadIdx.x;
  const int bc = blockIdx.y;
  const int b = bc / NC3, ch = bc % NC3;
  const int h0 = blockIdx.x * 8;
  const float* ib = in + (size_t)bc * NHW;
  for (int idx = t; idx < 10 * (NW + 2); idx += 256) {
    const int r = idx / (NW + 2), cc = idx % (NW + 2);
    const int gh = h0 + r - 1, gw = cc - 1;
    float v = 0.f;
    if (gh >= 0 && gh < NH && gw >= 0 && gw < NW) v = ib[gh * NW + gw];
    s[r][cc] = v;
  }
  __syncthreads();
  float wr[9];
#pragma unroll
  for (int k = 0; k < 9; ++k) wr[k] = w[ch * 9 + k];
  const float bs = bias[ch];
  if (ch < 192) {
    float* ob = out_qk + ((size_t)(b * 192 + ch)) * NHW + (size_t)h0 * NW + t;
#pragma unroll
    for (int r = 0; r < 8; ++r) {
      float a = bs;
#pragma unroll
      for (int dr = 0; dr < 3; ++dr)
#pragma unroll
        for (int dc = 0; dc < 3; ++dc)
          a = fmaf(s[r + dr][t + dc], wr[dr * 3 + dc], a);
      ob[r * NW] = a;
    }
  } else {
    const int bcv = b * NC + (ch - 192);
    const size_t base = (size_t)bcv * NHW + (size_t)(t >> 5) * 8192 + (t & 31);
#pragma unroll
    for (int r = 0; r < 8; ++r) {
      float a = bs;
#pragma unroll
      for (int dr = 0; dr < 3; ++dr)
#pragma unroll
        for (int dc = 0; dc < 3; ++dc)
          a = fmaf(s[r + dr][t + dc], wr[dr * 3 + dc], a);
      const ushort_t hi = f2bf(a);
      const ushort_t lo = f2bf(a - bf2f(hi));
      v_hi[base + (size_t)(h0 + r) * 32] = hi;
      v_lo[base + (size_t)(h0 + r) * 32] = lo;
    }
  }
}

// ---------------- prep: L2-norm over h + scale + bf16 split + transpose ----
// src [b*192 + qk*96 + c][h][w] fp32 -> qt/kt tiled [bc][hb][w][32h] bf16
__global__ __launch_bounds__(256) void k_prep(
    const float* __restrict__ src_qk, const float* __restrict__ temp,
    ushort_t* __restrict__ qt_hi, ushort_t* __restrict__ qt_lo,
    ushort_t* __restrict__ kt_hi, ushort_t* __restrict__ kt_lo) {
  __shared__ float trans[32][257];
  __shared__ float sums[8][32];
  __shared__ float inv[32];
  const int t = threadIdx.x;
  const int sw = blockIdx.x;  // 8 w-slabs of 32
  const int qk = blockIdx.y;
  const int bc = blockIdx.z;
  const int b = bc / NC, c = bc % NC;
  const float* src = src_qk + ((size_t)(b * 192 + qk * 96 + c)) * NHW + sw * 32;
  const int wl = t & 31, hg = t >> 5;
  float ss = 0.f;
  for (int i = 0; i < 32; ++i) {
    const int h = i * 8 + hg;
    const float v = src[(size_t)h * NW + wl];
    trans[wl][h] = v;
    ss = fmaf(v, v, ss);
  }
  sums[hg][wl] = ss;
  __syncthreads();
  if (t < 32) {
    float tot = 0.f;
#pragma unroll
    for (int g = 0; g < 8; ++g) tot += sums[g][t];
    float iv = 1.f / fmaxf(sqrtf(tot), 1e-12f);
    if (qk) iv *= temp[c];
    inv[t] = iv;
  }
  __syncthreads();
  const float iv = inv[wl];
  const int hb = hg;  // thread t handles h-block t>>5, w = t&31
  ushort_t* dh = (qk ? kt_hi : qt_hi) + (size_t)bc * NHW + (size_t)hb * 8192 +
                 (size_t)(sw * 32 + wl) * 32;
  ushort_t* dl = (qk ? kt_lo : qt_lo) + (size_t)bc * NHW + (size_t)hb * 8192 +
                 (size_t)(sw * 32 + wl) * 32;
#pragma unroll
  for (int j4 = 0; j4 < 4; ++j4) {
    uint4 ph, pl;
    unsigned* pph = (unsigned*)&ph;
    unsigned* ppl = (unsigned*)&pl;
#pragma unroll
    for (int e2 = 0; e2 < 4; ++e2) {
      const float f0 = trans[wl][hb * 32 + j4 * 8 + 2 * e2] * iv;
      const float f1 = trans[wl][hb * 32 + j4 * 8 + 2 * e2 + 1] * iv;
      const ushort_t h0 = f2bf(f0), h1 = f2bf(f1);
      const ushort_t l0 = f2bf(f0 - bf2f(h0)), l1 = f2bf(f1 - bf2f(h1));
      pph[e2] = (unsigned)h0 | ((unsigned)h1 << 16);
      ppl[e2] = (unsigned)l0 | ((unsigned)l1 << 16);
    }
    *(uint4*)(dh + j4 * 8) = ph;
    *(uint4*)(dl + j4 * 8) = pl;
  }
}

// ---------------- attn: S = QT*K (split-bf16 MFMA), col-softmax over w,
// write P transposed+split to pt_* tiled [bc][wb][v][32w] ----
__global__ __launch_bounds__(256, 3) void k_attn_mfma(
    const ushort_t* __restrict__ qt_hi, const ushort_t* __restrict__ qt_lo,
    const ushort_t* __restrict__ kt_hi, const ushort_t* __restrict__ kt_lo,
    ushort_t* __restrict__ pt_hi, ushort_t* __restrict__ pt_lo) {
  __shared__ __align__(16) char smem[52352];
  ushort_t* qh = (ushort_t*)smem;               // [256][40]
  ushort_t* ql = (ushort_t*)(smem + 20480);     // [256][40]
  ushort_t* kh = (ushort_t*)(smem + 40960);     // [64][40]
  ushort_t* kl = (ushort_t*)(smem + 46080);     // [64][40]
  float* red = (float*)(smem + 51200);          // [4][64]
  ushort_t* pts = (ushort_t*)smem;              // alias: [64][264]

  const int t = threadIdx.x;
  const int lane = t & 63;
  const int wid = t >> 6;
  const int bc = blockIdx.x;
  const int v0 = blockIdx.y * 64;
  const size_t base_q = (size_t)bc * NHW;
  const size_t base_k = (size_t)bc * NHW + (size_t)v0 * 32;

  f32x4 acc[4][4];
#pragma unroll
  for (int mt = 0; mt < 4; ++mt)
#pragma unroll
    for (int nt = 0; nt < 4; ++nt) acc[mt][nt] = (f32x4){0.f, 0.f, 0.f, 0.f};

  for (int hb = 0; hb < 8; ++hb) {
    {
      const ushort_t* gq = qt_hi + base_q + hb * 8192 + t * 32;
      const ushort_t* gl = qt_lo + base_q + hb * 8192 + t * 32;
      uint4* dh = (uint4*)(qh + t * 40);
      uint4* dl = (uint4*)(ql + t * 40);
#pragma unroll
      for (int j = 0; j < 4; ++j) {
        dh[j] = *(const uint4*)(gq + j * 8);
        dl[j] = *(const uint4*)(gl + j * 8);
      }
      if (t < 64) {
        const ushort_t* gk = kt_hi + base_k + hb * 8192 + t * 32;
        uint4* dk = (uint4*)(kh + t * 40);
#pragma unroll
        for (int j = 0; j < 4; ++j) dk[j] = *(const uint4*)(gk + j * 8);
      } else if (t < 128) {
        const int r = t - 64;
        const ushort_t* gk = kt_lo + base_k + hb * 8192 + r * 32;
        uint4* dk = (uint4*)(kl + r * 40);
#pragma unroll
        for (int j = 0; j < 4; ++j) dk[j] = *(const uint4*)(gk + j * 8);
      }
    }
    __syncthreads();
    bf16x8 aH[4], aL[4];
#pragma unroll
    for (int mt = 0; mt < 4; ++mt) {
      const int off = (wid * 64 + mt * 16 + (lane & 15)) * 40 + (lane >> 4) * 8;
      aH[mt] = *(const bf16x8*)(qh + off);
      aL[mt] = *(const bf16x8*)(ql + off);
    }
#pragma unroll
    for (int nt = 0; nt < 4; ++nt) {
      const int off = (nt * 16 + (lane & 15)) * 40 + (lane >> 4) * 8;
      const bf16x8 bH = *(const bf16x8*)(kh + off);
      const bf16x8 bL = *(const bf16x8*)(kl + off);
#pragma unroll
      for (int mt = 0; mt < 4; ++mt) {
        acc[mt][nt] = __builtin_amdgcn_mfma_f32_16x16x32_bf16(aH[mt], bH, acc[mt][nt], 0, 0, 0);
        acc[mt][nt] = __builtin_amdgcn_mfma_f32_16x16x32_bf16(aH[mt], bL, acc[mt][nt], 0, 0, 0);
        acc[mt][nt] = __builtin_amdgcn_mfma_f32_16x16x32_bf16(aL[mt], bH, acc[mt][nt], 0, 0, 0);
      }
    }
    __syncthreads();
  }

  // softmax over w (rows): C layout: col=lane&15 (v), row=(lane>>4)*4+r (w)
  float Mv[4], Sv[4];
#pragma unroll
  for (int nt = 0; nt < 4; ++nt) {
    float m = -3.4e38f;
#pragma unroll
    for (int mt = 0; mt < 4; ++mt)
#pragma unroll
      for (int r = 0; r < 4; ++r) m = fmaxf(m, acc[mt][nt][r]);
    m = fmaxf(m, __shfl_xor(m, 16));
    m = fmaxf(m, __shfl_xor(m, 32));
    if (lane < 16) red[wid * 64 + nt * 16 + lane] = m;
  }
  __syncthreads();
#pragma unroll
  for (int nt = 0; nt < 4; ++nt) {
    const int vl = nt * 16 + (lane & 15);
    Mv[nt] = fmaxf(fmaxf(red[vl], red[64 + vl]),
                   fmaxf(red[128 + vl], red[192 + vl]));
  }
  __syncthreads();
#pragma unroll
  for (int nt = 0; nt < 4; ++nt) {
    float s = 0.f;
#pragma unroll
    for (int mt = 0; mt < 4; ++mt)
#pragma unroll
      for (int r = 0; r < 4; ++r) {
        const float p = __expf(acc[mt][nt][r] - Mv[nt]);
        acc[mt][nt][r] = p;
        s += p;
      }
    s += __shfl_xor(s, 16);
    s += __shfl_xor(s, 32);
    if (lane < 16) red[wid * 64 + nt * 16 + lane] = s;
  }
  __syncthreads();
#pragma unroll
  for (int nt = 0; nt < 4; ++nt) {
    const int vl = nt * 16 + (lane & 15);
    Sv[nt] = 1.f / (red[vl] + red[64 + vl] + red[128 + vl] + red[192 + vl]);
  }
#pragma unroll
  for (int nt = 0; nt < 4; ++nt)
#pragma unroll
    for (int mt = 0; mt < 4; ++mt)
#pragma unroll
      for (int r = 0; r < 4; ++r) acc[mt][nt][r] *= Sv[nt];
  __syncthreads();  // staging fully dead before pts alias write

  // two passes: hi then lo, each staged through LDS for coalesced output
  for (int pass = 0; pass < 2; ++pass) {
#pragma unroll
    for (int nt = 0; nt < 4; ++nt)
#pragma unroll
      for (int mt = 0; mt < 4; ++mt) {
        ushort_t pk[4];
#pragma unroll
        for (int r = 0; r < 4; ++r) {
          const float p = acc[mt][nt][r];
          const ushort_t hi = f2bf(p);
          pk[r] = pass == 0 ? hi : f2bf(p - bf2f(hi));
        }
        const int v = nt * 16 + (lane & 15);
        const int wb2 = wid * 64 + mt * 16 + ((lane >> 4) << 2);
        *(ushort4*)(pts + v * 264 + wb2) =
            make_ushort4(pk[0], pk[1], pk[2], pk[3]);
      }
    __syncthreads();
    ushort_t* dst = pass == 0 ? pt_hi : pt_lo;
#pragma unroll
    for (int i = 0; i < 2; ++i) {
      const int cid = t + (i << 8);
      const int wb = cid >> 6, v = cid & 63;
      const ushort_t* sp = pts + v * 264 + wb * 32;
      ushort_t* d = dst + (size_t)bc * NHW + (size_t)wb * 8192 +
                    (size_t)(v0 + v) * 32;
#pragma unroll
      for (int j = 0; j < 4; ++j) *(uint4*)(d + j * 8) = *(const uint4*)(sp + j * 8);
    }
    __syncthreads();
  }
}

// ---------------- out[h][v] = sum_w V[h][w] * P[w][v], split-bf16 MFMA ----
__global__ __launch_bounds__(256, 3) void k_av_mfma(
    const ushort_t* __restrict__ v_hi, const ushort_t* __restrict__ v_lo,
    const ushort_t* __restrict__ pt_hi, const ushort_t* __restrict__ pt_lo,
    float* __restrict__ aout) {
  __shared__ __align__(16) ushort_t vh[128 * 40];
  __shared__ __align__(16) ushort_t vl[128 * 40];
  __shared__ __align__(16) ushort_t ph[128 * 40];
  __shared__ __align__(16) ushort_t pl[128 * 40];
  const int t = threadIdx.x;
  const int lane = t & 63;
  const int wid = t >> 6;
  const int bc = blockIdx.x;
  const int h0 = (blockIdx.y >> 1) * 128, v0 = (blockIdx.y & 1) * 128;
  const int wh = wid >> 1, wv = wid & 1;

  f32x4 acc[4][4];
#pragma unroll
  for (int mt = 0; mt < 4; ++mt)
#pragma unroll
    for (int nt = 0; nt < 4; ++nt) acc[mt][nt] = (f32x4){0.f, 0.f, 0.f, 0.f};

  for (int wb = 0; wb < 8; ++wb) {
#pragma unroll
    for (int i = 0; i < 2; ++i) {
      const int id = t + (i << 8);
      const int arr = id >> 7, row = id & 127;
      const ushort_t* g;
      ushort_t* d;
      if (arr == 0) {
        g = v_hi + (size_t)bc * NHW + (size_t)wb * 8192 + (size_t)(h0 + row) * 32;
        d = vh + row * 40;
      } else if (arr == 1) {
        g = v_lo + (size_t)bc * NHW + (size_t)wb * 8192 + (size_t)(h0 + row) * 32;
        d = vl + row * 40;
      } else if (arr == 2) {
        g = pt_hi + (size_t)bc * NHW + (size_t)wb * 8192 + (size_t)(v0 + row) * 32;
        d = ph + row * 40;
      } else {
        g = pt_lo + (size_t)bc * NHW + (size_t)wb * 8192 + (size_t)(v0 + row) * 32;
        d = pl + row * 40;
      }
#pragma unroll
      for (int j = 0; j < 4; ++j)
        *(uint4*)(d + j * 8) = *(const uint4*)(g + j * 8);
    }
    __syncthreads();
    bf16x8 aH[4], aL[4];
#pragma unroll
    for (int mt = 0; mt < 4; ++mt) {
      const int off = (wh * 64 + mt * 16 + (lane & 15)) * 40 + (lane >> 4) * 8;
      aH[mt] = *(const bf16x8*)(vh + off);
      aL[mt] = *(const bf16x8*)(vl + off);
    }
#pragma unroll
    for (int nt = 0; nt < 4; ++nt) {
      const int off = (wv * 64 + nt * 16 + (lane & 15)) * 40 + (lane >> 4) * 8;
      const bf16x8 bH = *(const bf16x8*)(ph + off);
      const bf16x8 bL = *(const bf16x8*)(pl + off);
#pragma unroll
      for (int mt = 0; mt < 4; ++mt) {
        acc[mt][nt] = __builtin_amdgcn_mfma_f32_16x16x32_bf16(aH[mt], bH, acc[mt][nt], 0, 0, 0);
        acc[mt][nt] = __builtin_amdgcn_mfma_f32_16x16x32_bf16(aH[mt], bL, acc[mt][nt], 0, 0, 0);
        acc[mt][nt] = __builtin_amdgcn_mfma_f32_16x16x32_bf16(aL[mt], bH, acc[mt][nt], 0, 0, 0);
      }
    }
    __syncthreads();
  }

#pragma unroll
  for (int mt = 0; mt < 4; ++mt) {
    const int hbase = h0 + wh * 64 + mt * 16 + ((lane >> 4) << 2);
#pragma unroll
    for (int nt = 0; nt < 4; ++nt) {
      const int vv = v0 + wv * 64 + nt * 16 + (lane & 15);
      float* o = aout + (size_t)bc * NHW + (size_t)hbase * NW + vv;
#pragma unroll
      for (int r = 0; r < 4; ++r) o[(size_t)r * NW] = acc[mt][nt][r];
    }
  }
}

extern "C" void kernel_launch(void* const* d_in, const int* in_sizes, int n_in,
                              void* d_out, int out_size, void* d_ws,
                              size_t ws_size, hipStream_t stream) {
  const float* x = (const float*)d_in[0];
  const float* qkv_w = (const float*)d_in[1];
  const float* qkv_b = (const float*)d_in[2];
  const float* dw_w = (const float*)d_in[3];
  const float* dw_b = (const float*)d_in[4];
  const float* temp = (const float*)d_in[5];
  const float* proj_w = (const float*)d_in[6];
  const float* proj_b = (const float*)d_in[7];
  float* out = (float*)d_out;

  // per-chunk: raw(288) f32 + dw_qk(192) f32 + V hi/lo bf16 = 151 MB * nb
  auto need = [](int nb) -> size_t {
    return (size_t)nb * NHW * 4ull * (NC3 + 192) + (size_t)nb * NC * NHW * 2ull * 2ull;
  };
  int nb = 1;
  if (need(4) <= ws_size) nb = 4;
  else if (need(2) <= ws_size) nb = 2;

  float* ws = (float*)d_ws;
  const size_t RAW = (size_t)nb * NC3 * NHW;
  const size_t QK = (size_t)nb * 192 * NHW;
  float* qkv_raw = ws;
  float* dw_qk = ws + RAW;
  ushort_t* v_hi = (ushort_t*)(ws + RAW + QK);
  ushort_t* v_lo = v_hi + (size_t)nb * NC * NHW;
  // aliases into dead regions:
  ushort_t* qt_hi = (ushort_t*)ws;                      // raw region (dead after dw)
  ushort_t* qt_lo = qt_hi + (size_t)nb * NC * NHW;
  ushort_t* kt_hi = qt_lo + (size_t)nb * NC * NHW;
  ushort_t* kt_lo = kt_hi + (size_t)nb * NC * NHW;
  ushort_t* pt_hi = (ushort_t*)dw_qk;                   // dw_qk dead after prep
  ushort_t* pt_lo = pt_hi + (size_t)nb * NC * NHW;
  float* aout = ws + (size_t)nb * NC * NHW * 2;         // raw tail (after qt/kt)

  const int BC = nb * NC;
  for (int b0 = 0; b0 < 4; b0 += nb) {
    const float* xb = x + (size_t)b0 * NC * NHW;
    float* outb = out + (size_t)b0 * NC * NHW;
    k_conv1x1<NC3><<<dim3(512, 3, nb), 256, 0, stream>>>(xb, qkv_w, qkv_b, qkv_raw);
    k_dw2<<<dim3(32, nb * NC3), 256, 0, stream>>>(qkv_raw, dw_w, dw_b, dw_qk, v_hi, v_lo);
    k_prep<<<dim3(8, 2, BC), 256, 0, stream>>>(dw_qk, temp, qt_hi, qt_lo, kt_hi, kt_lo);
    k_attn_mfma<<<dim3(BC, 4), 256, 0, stream>>>(qt_hi, qt_lo, kt_hi, kt_lo, pt_hi, pt_lo);
    k_av_mfma<<<dim3(BC, 4), 256, 0, stream>>>(v_hi, v_lo, pt_hi, pt_lo, aout);
    k_conv1x1<NC><<<dim3(512, 1, nb), 256, 0, stream>>>(aout, proj_w, proj_b, outb);
  }
}